// Round 3
// baseline (99.643 us; speedup 1.0000x reference)
//
#include <hip/hip_runtime.h>
#include <hip/hip_fp16.h>
#include <stdint.h>

#define H_ 120
#define W_ 160
#define HW_ (H_*W_)          // 19200
#define SKIP_ 8
#define P_ (HW_/SKIP_)       // 2400 voting pixels
#define NC_ 8                // classes
#define PADCAP_ (P_ + NC_*16) // 2528: per-class segments padded to mult of 16
#define THR2_ 0.81f          // 0.9^2
#define EPSV_ 1e-6f
#define LPB_ 32              // Hough locations per block in k_vote
#define NBLK_ (HW_/LPB_)     // 600 blocks per batch image

typedef unsigned long long ull;

// ---------------- Kernel 1: preprocess + class-compact voting pixels ----------------
// Packs per valid pixel: float4(nx, ny, half2(xs,ys), depth). Segments grouped by
// class, each padded to a multiple of 16 with zeros (nx=ny=0 -> dot=0 -> never inlier).
__global__ __launch_bounds__(1024) void k_prep(
    const int* __restrict__ labels, const int* __restrict__ masks,
    const float* __restrict__ vp,
    float4* __restrict__ arr4, int* __restrict__ clsStartPad,
    int* __restrict__ nvalid)
{
    int b = blockIdx.x;
    labels += (size_t)b * HW_;
    masks  += (size_t)b * HW_;
    vp     += (size_t)b * 3 * NC_ * HW_;
    float4* a4 = arr4 + (size_t)b * PADCAP_;

    __shared__ int s_cnt[NC_];
    __shared__ int s_off[NC_];
    __shared__ int s_start[NC_ + 1];
    int t = threadIdx.x;
    if (t < NC_) s_cnt[t] = 0;
    // zero whole padded array (pad slots must be "never-inlier")
    float4 z4 = make_float4(0.f, 0.f, 0.f, 0.f);
    for (int i = t; i < PADCAP_; i += 1024) a4[i] = z4;
    __syncthreads();
    for (int p = t; p < P_; p += 1024) {
        int idx = p * SKIP_;
        int lab = labels[idx];
        if (masks[idx] > 0 && lab > 0) atomicAdd(&s_cnt[lab], 1);
    }
    __syncthreads();
    if (t == 0) {
        int acc = 0;
        for (int c = 0; c < NC_; ++c) { s_start[c] = acc; acc += (s_cnt[c] + 15) & ~15; }
        s_start[NC_] = acc;
    }
    __syncthreads();
    if (t < NC_) s_off[t] = s_start[t];
    if (t < NC_ + 1) clsStartPad[b*(NC_+1) + t] = s_start[t];
    if (t < NC_) nvalid[b*NC_ + t] = s_cnt[t];     // true (unpadded) per-class voter count
    __syncthreads();
    for (int p = t; p < P_; p += 1024) {
        int idx = p * SKIP_;
        int lab = labels[idx];
        if (masks[idx] > 0 && lab > 0) {
            int xi = idx % W_, yi = idx / W_;
            float xs = (float)xi, ys = (float)yi;
            float vx = vp[(lab*3 + 0)*HW_ + idx];
            float vy = vp[(lab*3 + 1)*HW_ + idx];
            float vz = vp[(lab*3 + 2)*HW_ + idx];
            float nrm = sqrtf(vx*vx + vy*vy) + EPSV_;
            float nx = vx / nrm, ny = vy / nrm;
            float depth = expf(vz);
            unsigned hx = __half_as_ushort(__float2half_rn(xs));  // exact: ints < 2048
            unsigned hy = __half_as_ushort(__float2half_rn(ys));
            int pos = atomicAdd(&s_off[lab], 1);
            a4[pos] = make_float4(nx, ny, __uint_as_float(hx | (hy << 16)), depth);
        }
    }
}

// ---------------- Kernel 2: Hough voting (pure compute, no device atomics) ----------------
// grid: (NBLK_, B), block 256. Thread t: L = bx*32 + (t>>3), pixel chunk = t&7.
// Each block writes its local best per class to a private slot; k_final reduces.
__global__ __launch_bounds__(256) void k_vote(
    const float4* __restrict__ arr4, const int* __restrict__ clsStartPad,
    ull* __restrict__ bslot)
{
    int b = blockIdx.y;
    const float4* a4 = arr4 + (size_t)b * PADCAP_;

    __shared__ float4 s_a[PADCAP_];   // 40448 B -> ~4 blocks/CU
    __shared__ int s_start[NC_ + 1];
    __shared__ ull s_best[NC_];

    int t = threadIdx.x;
    if (t < NC_ + 1) s_start[t] = clsStartPad[b*(NC_+1) + t];
    if (t < NC_) s_best[t] = 0ULL;
    __syncthreads();
    int nvp = s_start[NC_];
    for (int i = t; i < nvp; i += 256) s_a[i] = a4[i];
    __syncthreads();

    int L = blockIdx.x * LPB_ + (t >> 3);
    int chunk = t & 7;
    float gx = (float)(L % W_), gy = (float)(L / W_);

    int   cnt[NC_];
    float ds[NC_];
    #pragma unroll
    for (int c = 0; c < NC_; ++c) {
        int lo = s_start[c], hi = s_start[c+1];   // hi-lo is a multiple of 16
        int cc = 0; float dd = 0.f;
        for (int j = lo + chunk; j < hi; j += 16) {
            // two independent evals per step -> 2 ds_read_b128 in flight
            float4 a0 = s_a[j];
            float4 a1 = s_a[j + 8];
            {
                unsigned u = __float_as_uint(a0.z);
                float xs = __half2float(__ushort_as_half((unsigned short)(u & 0xffffu)));
                float ys = __half2float(__ushort_as_half((unsigned short)(u >> 16)));
                float dx = gx - xs, dy = gy - ys;
                float dot = fmaf(dx, a0.x, dy * a0.y);
                float d2  = fmaf(dx, dx, dy * dy);
                bool in = (dot > 0.f) && (dot * dot > THR2_ * d2);
                cc += in ? 1 : 0;
                dd += in ? a0.w : 0.f;
            }
            {
                unsigned u = __float_as_uint(a1.z);
                float xs = __half2float(__ushort_as_half((unsigned short)(u & 0xffffu)));
                float ys = __half2float(__ushort_as_half((unsigned short)(u >> 16)));
                float dx = gx - xs, dy = gy - ys;
                float dot = fmaf(dx, a1.x, dy * a1.y);
                float d2  = fmaf(dx, dx, dy * dy);
                bool in = (dot > 0.f) && (dot * dot > THR2_ * d2);
                cc += in ? 1 : 0;
                dd += in ? a1.w : 0.f;
            }
        }
        cnt[c] = cc; ds[c] = dd;
    }
    // combine the 8 pixel-chunks (lanes t&7 share L)
    #pragma unroll
    for (int c = 0; c < NC_; ++c) {
        cnt[c] += __shfl_xor(cnt[c], 1);
        cnt[c] += __shfl_xor(cnt[c], 2);
        cnt[c] += __shfl_xor(cnt[c], 4);
        ds[c]  += __shfl_xor(ds[c], 1);
        ds[c]  += __shfl_xor(ds[c], 2);
        ds[c]  += __shfl_xor(ds[c], 4);
    }
    // wave-level argmax on packed key, then one LDS atomic per wave per class
    #pragma unroll
    for (int c = 0; c < NC_; ++c) {
        // key: votes (<=2400, 12 bits) << 15 | (HW-1-L): max == argmax w/ lowest-L tiebreak
        unsigned key = ((unsigned)cnt[c] << 15) | (unsigned)(HW_ - 1 - L);
        ull pk = ((ull)key << 32) | (ull)__float_as_uint(ds[c]);
        ull q;
        q = __shfl_xor(pk, 8);  pk = pk > q ? pk : q;
        q = __shfl_xor(pk, 16); pk = pk > q ? pk : q;
        q = __shfl_xor(pk, 32); pk = pk > q ? pk : q;
        if ((t & 63) == 0) atomicMax(&s_best[c], pk);
    }
    __syncthreads();
    // private per-block slot: no contention, no fence needed (cross-kernel stream order)
    if (t < NC_) bslot[((size_t)b * NBLK_ + blockIdx.x) * NC_ + t] = s_best[t];
}

// ---------------- Kernel 3: reduce per-block winners + finalize boxes/poses ----------------
// 1 block, 256 threads. Group g (32 threads) reduces one (b,c) pair at a time.
__global__ __launch_bounds__(256) void k_final(
    const ull* __restrict__ bslot, const int* __restrict__ nvalid,
    const float* __restrict__ extents, const float* __restrict__ poses,
    const float* __restrict__ meta, float* __restrict__ out, int B)
{
    int t = threadIdx.x;
    int g = t >> 5, lane = t & 31;
    int npairs = B * NC_;
    for (int p = g; p < npairs; p += 8) {
        int bb = p / NC_, c = p % NC_;
        const ull* sl = bslot + (size_t)bb * NBLK_ * NC_ + c;
        ull pk = 0ULL;
        for (int j = lane; j < NBLK_; j += 32) {
            ull v = sl[(size_t)j * NC_];
            pk = pk > v ? pk : v;
        }
        ull q;
        q = __shfl_xor(pk, 1);  pk = pk > q ? pk : q;
        q = __shfl_xor(pk, 2);  pk = pk > q ? pk : q;
        q = __shfl_xor(pk, 4);  pk = pk > q ? pk : q;
        q = __shfl_xor(pk, 8);  pk = pk > q ? pk : q;
        q = __shfl_xor(pk, 16); pk = pk > q ? pk : q;
        if (lane == 0) {
            unsigned key = (unsigned)(pk >> 32);
            int Lw = (HW_ - 1) - (int)(key & 0x7FFFu);
            float vmax = (float)(key >> 15);
            float dsum = __uint_as_float((unsigned)(pk & 0xFFFFFFFFull));
            float nv = (float)nvalid[p];
            float dbar = dsum / fmaxf(vmax, 1.0f);
            float cx = (float)(Lw % W_), cy = (float)(Lw / W_);
            float fx = meta[bb*9 + 0], px = meta[bb*9 + 2];
            float fy = meta[bb*9 + 4], py = meta[bb*9 + 5];
            float e0 = extents[c*3 + 0], e1 = extents[c*3 + 1], e2 = extents[c*3 + 2];
            float diag = sqrtf(e0*e0 + e1*e1 + e2*e2);
            float safe_d = fmaxf(dbar, EPSV_);
            float bw = diag * fx / safe_d;
            float bh = diag * fy / safe_d;
            float score = vmax / fmaxf(nv, 1.0f);

            float* ob = out + (size_t)p * 7;
            ob[0] = (float)bb;
            ob[1] = (float)c;
            ob[2] = cx - bw * 0.5f;
            ob[3] = cy - bh * 0.5f;
            ob[4] = cx + bw * 0.5f;
            ob[5] = cy + bh * 0.5f;
            ob[6] = score;

            float* op = out + (size_t)B * NC_ * 7 + (size_t)p * 7;
            op[0] = poses[p*7 + 0];
            op[1] = poses[p*7 + 1];
            op[2] = poses[p*7 + 2];
            op[3] = poses[p*7 + 3];
            op[4] = (cx - px) * dbar / fmaxf(fx, EPSV_);
            op[5] = (cy - py) * dbar / fmaxf(fy, EPSV_);
            op[6] = dbar;
        }
    }
}

extern "C" void kernel_launch(void* const* d_in, const int* in_sizes, int n_in,
                              void* d_out, int out_size, void* d_ws, size_t ws_size,
                              hipStream_t stream)
{
    const int*   labels  = (const int*)d_in[0];
    const int*   masks   = (const int*)d_in[1];
    const float* vp      = (const float*)d_in[2];
    const float* extents = (const float*)d_in[3];
    const float* poses   = (const float*)d_in[4];
    const float* meta    = (const float*)d_in[5];
    int B = in_sizes[0] / HW_;

    // workspace layout (16B-aligned first)
    float4*   arr4     = (float4*)d_ws;                            // B*PADCAP_ float4
    ull*      bslot    = (ull*)(arr4 + (size_t)B * PADCAP_);       // B*NBLK_*NC_ ull
    int*      clsStart = (int*)(bslot + (size_t)B * NBLK_ * NC_);  // B*(NC+1) int
    int*      nvalid   = clsStart + (size_t)B * (NC_ + 1);         // B*NC int
    float*    out      = (float*)d_out;

    k_prep<<<B, 1024, 0, stream>>>(labels, masks, vp, arr4, clsStart, nvalid);
    k_vote<<<dim3(NBLK_, B), 256, 0, stream>>>(arr4, clsStart, bslot);
    k_final<<<1, 256, 0, stream>>>(bslot, nvalid, extents, poses, meta, out, B);
}

// Round 4
// 96.154 us; speedup vs baseline: 1.0363x; 1.0363x over previous
//
#include <hip/hip_runtime.h>
#include <hip/hip_fp16.h>
#include <stdint.h>

#define H_ 120
#define W_ 160
#define HW_ (H_*W_)          // 19200
#define SKIP_ 8
#define P_ (HW_/SKIP_)       // 2400 voting pixels
#define NC_ 8                // classes
#define PADCAP_ (P_ + NC_*16) // 2528: per-class segments padded to mult of 16
#define THR2_ 0.81f          // 0.9^2
#define EPSV_ 1e-6f
#define LPB_ 32              // Hough locations per block in k_vote
#define NBLK_ (HW_/LPB_)     // 600 blocks per batch image

typedef unsigned long long ull;

// ---------------- Kernel 1: preprocess + class-compact voting pixels ----------------
// grid (NC_, B): block c compacts class c. All blocks redundantly histogram the
// (L2-resident, 19 KB) label/mask stream -> identical s_start in every block, no
// cross-block sync. Packs per voter: float4(nx, ny, half2(xs,ys), depth).
__global__ __launch_bounds__(256) void k_prep(
    const int* __restrict__ labels, const int* __restrict__ masks,
    const float* __restrict__ vp,
    float4* __restrict__ arr4, int* __restrict__ clsStartPad,
    int* __restrict__ nvalid)
{
    int c = blockIdx.x;          // class this block owns
    int b = blockIdx.y;
    labels += (size_t)b * HW_;
    masks  += (size_t)b * HW_;
    vp     += (size_t)b * 3 * NC_ * HW_;
    float4* a4 = arr4 + (size_t)b * PADCAP_;

    __shared__ int s_cnt[NC_];
    __shared__ int s_start[NC_ + 1];
    __shared__ int s_off;
    int t = threadIdx.x;
    if (t < NC_) s_cnt[t] = 0;
    __syncthreads();
    for (int p = t; p < P_; p += 256) {
        int idx = p * SKIP_;
        int lab = labels[idx];
        if (masks[idx] > 0 && lab > 0) atomicAdd(&s_cnt[lab], 1);
    }
    __syncthreads();
    if (t == 0) {
        int acc = 0;
        for (int k = 0; k < NC_; ++k) { s_start[k] = acc; acc += (s_cnt[k] + 15) & ~15; }
        s_start[NC_] = acc;
        s_off = s_start[c];
    }
    __syncthreads();
    if (c == 0) {   // block 0 publishes metadata (identical in all blocks)
        if (t < NC_ + 1) clsStartPad[b*(NC_+1) + t] = s_start[t];
        if (t < NC_) nvalid[b*NC_ + t] = s_cnt[t];
    }
    // zero my class's pad tail (pad voters are all-zero -> dot==0 -> never inlier)
    {
        int lo = s_start[c] + s_cnt[c], hi = s_start[c+1];
        float4 z4 = make_float4(0.f, 0.f, 0.f, 0.f);
        for (int i = lo + t; i < hi; i += 256) a4[i] = z4;
    }
    // compact my class's voters
    for (int p = t; p < P_; p += 256) {
        int idx = p * SKIP_;
        int lab = labels[idx];
        if (masks[idx] > 0 && lab > 0 && lab == c) {
            int xi = idx % W_, yi = idx / W_;
            float xs = (float)xi, ys = (float)yi;
            float vx = vp[(lab*3 + 0)*HW_ + idx];
            float vy = vp[(lab*3 + 1)*HW_ + idx];
            float vz = vp[(lab*3 + 2)*HW_ + idx];
            float nrm = sqrtf(vx*vx + vy*vy) + EPSV_;
            float nx = vx / nrm, ny = vy / nrm;
            float depth = expf(vz);
            unsigned hx = __half_as_ushort(__float2half_rn(xs));  // exact: ints < 2048
            unsigned hy = __half_as_ushort(__float2half_rn(ys));
            int pos = atomicAdd(&s_off, 1);
            a4[pos] = make_float4(nx, ny, __uint_as_float(hx | (hy << 16)), depth);
        }
    }
}

// ---------------- Kernel 2: Hough voting, counts only ----------------
// grid (NBLK_, B), 256 threads. Thread: quad = t>>5 (4 consecutive Ls), chunk = t&31.
// One ds_read_b128 feeds 4 inlier tests; depth sums deferred to k_final.
__global__ __launch_bounds__(256, 4) void k_vote(
    const float4* __restrict__ arr4, const int* __restrict__ clsStartPad,
    unsigned* __restrict__ bslot)
{
    int b = blockIdx.y;
    const float4* a4 = arr4 + (size_t)b * PADCAP_;

    __shared__ float4 s_a[PADCAP_];   // 40448 B -> 4 blocks/CU
    __shared__ int s_start[NC_ + 1];
    __shared__ unsigned s_best[NC_];

    int t = threadIdx.x;
    if (t < NC_ + 1) s_start[t] = clsStartPad[b*(NC_+1) + t];
    if (t < NC_) s_best[t] = 0u;
    __syncthreads();
    int nvp = s_start[NC_];
    for (int i = t; i < nvp; i += 256) s_a[i] = a4[i];
    __syncthreads();

    int quad  = t >> 5;               // 0..7 -> Ls [L0, L0+3]
    int chunk = t & 31;               // voter chunk
    int L0 = blockIdx.x * LPB_ + quad * 4;
    float gx0 = (float)(L0 % W_);     // 4 | 32 | W  ->  quad stays in one row
    float gy  = (float)(L0 / W_);

    unsigned cp01[NC_], cp23[NC_];    // packed counts: L0|L1<<16, L2|L3<<16
    #pragma unroll
    for (int c = 0; c < NC_; ++c) {
        int lo = s_start[c], hi = s_start[c+1];
        unsigned p01 = 0u, p23 = 0u;
        #pragma unroll 2
        for (int j = lo + chunk; j < hi; j += 32) {
            float4 a = s_a[j];
            unsigned u = __float_as_uint(a.z);
            float xs = __half2float(__ushort_as_half((unsigned short)(u & 0xffffu)));
            float ys = __half2float(__ushort_as_half((unsigned short)(u >> 16)));
            float dy  = gy - ys;
            float tdy = dy * a.y;     // dy*ny  (same mul/fma sequence as verified kernel)
            float dy2 = dy * dy;
            float dx0 = gx0 - xs;     // integer-valued; dx_i = dx0 + i is exact
            {
                float dot = fmaf(dx0, a.x, tdy);
                float d2  = fmaf(dx0, dx0, dy2);
                p01 += ((dot > 0.f) && (dot*dot > THR2_*d2)) ? 1u : 0u;
            }
            {
                float dx = dx0 + 1.0f;
                float dot = fmaf(dx, a.x, tdy);
                float d2  = fmaf(dx, dx, dy2);
                p01 += ((dot > 0.f) && (dot*dot > THR2_*d2)) ? 0x10000u : 0u;
            }
            {
                float dx = dx0 + 2.0f;
                float dot = fmaf(dx, a.x, tdy);
                float d2  = fmaf(dx, dx, dy2);
                p23 += ((dot > 0.f) && (dot*dot > THR2_*d2)) ? 1u : 0u;
            }
            {
                float dx = dx0 + 3.0f;
                float dot = fmaf(dx, a.x, tdy);
                float d2  = fmaf(dx, dx, dy2);
                p23 += ((dot > 0.f) && (dot*dot > THR2_*d2)) ? 0x10000u : 0u;
            }
        }
        cp01[c] = p01; cp23[c] = p23;
    }
    // sum the 32 voter-chunks (lanes t&31 share the quad); fields < 2^16, no carry
    #pragma unroll
    for (int c = 0; c < NC_; ++c) {
        #pragma unroll
        for (int s = 1; s <= 16; s <<= 1) {
            cp01[c] += __shfl_xor(cp01[c], s);
            cp23[c] += __shfl_xor(cp23[c], s);
        }
    }
    // per-class argmax: key = cnt<<15 | (HW-1-L) -> max == argmax, lowest-L tiebreak
    #pragma unroll
    for (int c = 0; c < NC_; ++c) {
        unsigned k0 = ((cp01[c] & 0xffffu) << 15) | (unsigned)(HW_ - 1 - L0);
        unsigned k1 = ((cp01[c] >> 16)     << 15) | (unsigned)(HW_ - 2 - L0);
        unsigned k2 = ((cp23[c] & 0xffffu) << 15) | (unsigned)(HW_ - 3 - L0);
        unsigned k3 = ((cp23[c] >> 16)     << 15) | (unsigned)(HW_ - 4 - L0);
        unsigned km = k0 > k1 ? k0 : k1;
        km = km > k2 ? km : k2;
        km = km > k3 ? km : k3;
        unsigned q = __shfl_xor(km, 32);   // combine the 2 quads in the wave
        km = km > q ? km : q;
        if ((t & 63) == 0) atomicMax(&s_best[c], km);
    }
    __syncthreads();
    if (t < NC_) bslot[((size_t)b * NBLK_ + blockIdx.x) * NC_ + t] = s_best[t];
}

// ---------------- Kernel 3: reduce winners, recompute dsum at winner, finalize ----------------
// 1 block, 256 threads; 32-lane group g handles (b,c) pair g.
__global__ __launch_bounds__(256) void k_final(
    const unsigned* __restrict__ bslot, const int* __restrict__ clsStartPad,
    const float4* __restrict__ arr4, const int* __restrict__ nvalid,
    const float* __restrict__ extents, const float* __restrict__ poses,
    const float* __restrict__ meta, float* __restrict__ out, int B)
{
    int t = threadIdx.x;
    int g = t >> 5, lane = t & 31;
    int npairs = B * NC_;
    for (int p = g; p < npairs; p += 8) {
        int bb = p / NC_, c = p % NC_;
        const unsigned* sl = bslot + ((size_t)bb * NBLK_) * NC_ + c;
        unsigned key = 0u;
        for (int j = lane; j < NBLK_; j += 32) {
            unsigned v = sl[(size_t)j * NC_];
            key = key > v ? key : v;
        }
        #pragma unroll
        for (int s = 1; s <= 16; s <<= 1) {
            unsigned q = __shfl_xor(key, s);
            key = key > q ? key : q;
        }
        int Lw = (HW_ - 1) - (int)(key & 0x7FFFu);
        float vmax = (float)(key >> 15);
        // recompute depth sum at the winning location over class-c's segment (L2-hot)
        int lo = clsStartPad[bb*(NC_+1) + c];
        int hi = clsStartPad[bb*(NC_+1) + c + 1];
        const float4* a4 = arr4 + (size_t)bb * PADCAP_;
        float gx = (float)(Lw % W_), gy = (float)(Lw / W_);
        float dd = 0.f;
        for (int j = lo + lane; j < hi; j += 32) {
            float4 a = a4[j];
            unsigned u = __float_as_uint(a.z);
            float xs = __half2float(__ushort_as_half((unsigned short)(u & 0xffffu)));
            float ys = __half2float(__ushort_as_half((unsigned short)(u >> 16)));
            float dx = gx - xs, dy = gy - ys;
            float dot = fmaf(dx, a.x, dy * a.y);
            float d2  = fmaf(dx, dx, dy * dy);
            bool in = (dot > 0.f) && (dot * dot > THR2_ * d2);
            dd += in ? a.w : 0.f;
        }
        #pragma unroll
        for (int s = 1; s <= 16; s <<= 1) dd += __shfl_xor(dd, s);
        if (lane == 0) {
            float nv = (float)nvalid[p];
            float dbar = dd / fmaxf(vmax, 1.0f);
            float cx = (float)(Lw % W_), cy = (float)(Lw / W_);
            float fx = meta[bb*9 + 0], px = meta[bb*9 + 2];
            float fy = meta[bb*9 + 4], py = meta[bb*9 + 5];
            float e0 = extents[c*3 + 0], e1 = extents[c*3 + 1], e2 = extents[c*3 + 2];
            float diag = sqrtf(e0*e0 + e1*e1 + e2*e2);
            float safe_d = fmaxf(dbar, EPSV_);
            float bw = diag * fx / safe_d;
            float bh = diag * fy / safe_d;
            float score = vmax / fmaxf(nv, 1.0f);

            float* ob = out + (size_t)p * 7;
            ob[0] = (float)bb;
            ob[1] = (float)c;
            ob[2] = cx - bw * 0.5f;
            ob[3] = cy - bh * 0.5f;
            ob[4] = cx + bw * 0.5f;
            ob[5] = cy + bh * 0.5f;
            ob[6] = score;

            float* op = out + (size_t)B * NC_ * 7 + (size_t)p * 7;
            op[0] = poses[p*7 + 0];
            op[1] = poses[p*7 + 1];
            op[2] = poses[p*7 + 2];
            op[3] = poses[p*7 + 3];
            op[4] = (cx - px) * dbar / fmaxf(fx, EPSV_);
            op[5] = (cy - py) * dbar / fmaxf(fy, EPSV_);
            op[6] = dbar;
        }
    }
}

extern "C" void kernel_launch(void* const* d_in, const int* in_sizes, int n_in,
                              void* d_out, int out_size, void* d_ws, size_t ws_size,
                              hipStream_t stream)
{
    const int*   labels  = (const int*)d_in[0];
    const int*   masks   = (const int*)d_in[1];
    const float* vp      = (const float*)d_in[2];
    const float* extents = (const float*)d_in[3];
    const float* poses   = (const float*)d_in[4];
    const float* meta    = (const float*)d_in[5];
    int B = in_sizes[0] / HW_;

    // workspace layout (16B-aligned first)
    float4*   arr4     = (float4*)d_ws;                              // B*PADCAP_ float4
    unsigned* bslot    = (unsigned*)(arr4 + (size_t)B * PADCAP_);    // B*NBLK_*NC_ uint
    int*      clsStart = (int*)(bslot + (size_t)B * NBLK_ * NC_);    // B*(NC+1) int
    int*      nvalid   = clsStart + (size_t)B * (NC_ + 1);           // B*NC int
    float*    out      = (float*)d_out;

    k_prep<<<dim3(NC_, B), 256, 0, stream>>>(labels, masks, vp, arr4, clsStart, nvalid);
    k_vote<<<dim3(NBLK_, B), 256, 0, stream>>>(arr4, clsStart, bslot);
    k_final<<<1, 256, 0, stream>>>(bslot, clsStart, arr4, nvalid, extents, poses, meta, out, B);
}